// Round 9
// baseline (1926.501 us; speedup 1.0000x reference)
//
#include <hip/hip_runtime.h>
#include <cstddef>

#define Cc 96
#define CH 384
#define Mtok 262144   // B*H*W = 16*128*128
#define Mi   16384    // tokens per image

typedef unsigned short us8 __attribute__((ext_vector_type(8)));
typedef float f8 __attribute__((ext_vector_type(8)));
typedef short s8v __attribute__((ext_vector_type(8)));
typedef float f4v __attribute__((ext_vector_type(4)));

static __device__ __forceinline__ float b2f(unsigned short s){
  union { unsigned u; float f; } v; v.u = ((unsigned)s) << 16; return v.f;
}
static __device__ __forceinline__ unsigned short f2b(float f){
  union { float f; unsigned u; } v; v.f = f;
  unsigned r = v.u + 0x7fffu + ((v.u >> 16) & 1u);
  return (unsigned short)(r >> 16);
}

// ---------------- K0a: transpose dw_w [c][tap] -> wt_t [tap][c] ----------------
__global__ __launch_bounds__(64) void k_wprep(const float* __restrict__ dww,
    float* __restrict__ wt_t){
  int i = blockIdx.x*64 + threadIdx.x;   // i = tap*CH + c
  if (i < 9*CH){
    int tap = i / CH, c = i - tap*CH;
    wt_t[i] = dww[c*9 + tap];
  }
}

// ---------------- K0b: pack fc2_w [384][96] f32 -> bf16 MFMA b-frag layout ----
__global__ __launch_bounds__(256) void k_wprep2(const float* __restrict__ fc2w,
    unsigned short* __restrict__ Bp){
  int i = blockIdx.x*256 + threadIdx.x;   // < 6*12*64*8 = 36864
  int j = i & 7;
  int t = i >> 3;
  int l = t & 63;
  int u = t >> 6;          // 0..71
  int ks = u % 12, nt = u / 12;
  int k   = ks*32 + (l>>4)*8 + j;
  int col = nt*16 + (l&15);
  Bp[i] = f2b(fc2w[(size_t)k*96 + col]);
}

// ---------------- K1: gate-H softmax weights  wh[5][Mloc] ----------------
__global__ __launch_bounds__(256) void k_gate_h(const float* __restrict__ x,
    const float* __restrict__ gh_w, const float* __restrict__ gh_b,
    float* __restrict__ wh, int base, int Mloc){
  int m = blockIdx.x*256 + threadIdx.x;
  const float* xr = x + (size_t)(base + m)*Cc;
  float l[5];
  #pragma unroll
  for (int s=0;s<5;++s) l[s] = gh_b[s];
  #pragma unroll
  for (int c=0;c<Cc;c+=4){
    float4 xv = *(const float4*)(xr+c);
    #pragma unroll
    for (int s=0;s<5;++s){
      float4 g = *(const float4*)(gh_w + s*Cc + c);
      l[s]=fmaf(xv.x,g.x,l[s]); l[s]=fmaf(xv.y,g.y,l[s]);
      l[s]=fmaf(xv.z,g.z,l[s]); l[s]=fmaf(xv.w,g.w,l[s]);
    }
  }
  float mx = fmaxf(fmaxf(fmaxf(l[0],l[1]),fmaxf(l[2],l[3])),l[4]);
  float sum=0.f;
  #pragma unroll
  for (int s=0;s<5;++s){ l[s]=__expf(l[s]-mx); sum+=l[s]; }
  float inv = 1.f/sum;
  #pragma unroll
  for (int s=0;s<5;++s) wh[(size_t)s*Mloc + m] = l[s]*inv;
}

// ---------------- K2: fused H-shift-mix + fc1 GEMM -> hid (bf16) ----------------
__global__ __launch_bounds__(256) void k_fc1(const float* __restrict__ x,
    const float* __restrict__ wh, const float* __restrict__ fc1w,
    const float* __restrict__ fc1b, unsigned short* __restrict__ hid,
    int base, int Mloc){
  __shared__ float As[64][100];
  __shared__ float Bs[16*CH];     // one 16-row K-chunk of fc1w, flat
  const int tid = threadIdx.x;
  const int nwg = gridDim.x;
  const int cpx = nwg >> 3;
  const int bid = (int)blockIdx.x;
  const int wg  = (bid & 7)*cpx + (bid >> 3);
  const int m0 = wg*64;
  {
    int sr = tid>>2, sq = tid&3;
    int ml = m0 + sr;              // local token
    int gm = base + ml;            // global token
    int sh = (gm>>7)&127;          // h coordinate
    float swgt[5];
    #pragma unroll
    for (int i=0;i<5;++i){
      int h2 = sh - (i-2);
      swgt[i] = ((unsigned)h2 < 128u) ? wh[(size_t)i*Mloc + ml] : 0.f;
    }
    #pragma unroll
    for (int j=0;j<6;++j){
      int c = sq*24 + j*4;
      float4 a = make_float4(0.f,0.f,0.f,0.f);
      #pragma unroll
      for (int i=0;i<5;++i){
        if (swgt[i] != 0.f){
          float4 xv = *(const float4*)&x[(size_t)(gm - (i-2)*128)*Cc + c];
          a.x=fmaf(swgt[i],xv.x,a.x); a.y=fmaf(swgt[i],xv.y,a.y);
          a.z=fmaf(swgt[i],xv.z,a.z); a.w=fmaf(swgt[i],xv.w,a.w);
        }
      }
      *(float4*)&As[sr][c] = a;
    }
  }
  const int tx = tid&15, ty = tid>>4;
  float acc[4][24];
  #pragma unroll
  for (int i=0;i<4;++i)
    #pragma unroll
    for (int j=0;j<24;++j) acc[i][j] = 0.f;

  for (int kc=0;kc<6;++kc){
    const float4* src = (const float4*)(fc1w + (size_t)kc*16*CH);
    float4* dst = (float4*)Bs;
    #pragma unroll
    for (int p=0;p<6;++p) dst[tid + p*256] = src[tid + p*256];
    __syncthreads();
    #pragma unroll
    for (int q=0;q<4;++q){
      float4 av[4];
      #pragma unroll
      for (int i=0;i<4;++i) av[i] = *(const float4*)&As[ty*4+i][kc*16 + q*4];
      #pragma unroll
      for (int kk=0;kk<4;++kk){
        float4 bv[6];
        #pragma unroll
        for (int j=0;j<6;++j) bv[j] = *(const float4*)&Bs[(q*4+kk)*CH + tx*4 + 64*j];
        #pragma unroll
        for (int i=0;i<4;++i){
          float a = (kk==0)?av[i].x:(kk==1)?av[i].y:(kk==2)?av[i].z:av[i].w;
          #pragma unroll
          for (int j=0;j<6;++j){
            acc[i][j*4+0]=fmaf(a,bv[j].x,acc[i][j*4+0]);
            acc[i][j*4+1]=fmaf(a,bv[j].y,acc[i][j*4+1]);
            acc[i][j*4+2]=fmaf(a,bv[j].z,acc[i][j*4+2]);
            acc[i][j*4+3]=fmaf(a,bv[j].w,acc[i][j*4+3]);
          }
        }
      }
    }
    __syncthreads();
  }
  float4 bb[6];
  #pragma unroll
  for (int j=0;j<6;++j) bb[j] = *(const float4*)&fc1b[tx*4 + 64*j];
  #pragma unroll
  for (int i=0;i<4;++i){
    size_t m = (size_t)(m0 + ty*4 + i);
    #pragma unroll
    for (int j=0;j<6;++j){
      ushort4 pk;
      pk.x = f2b(acc[i][j*4+0]+bb[j].x);
      pk.y = f2b(acc[i][j*4+1]+bb[j].y);
      pk.z = f2b(acc[i][j*4+2]+bb[j].z);
      pk.w = f2b(acc[i][j*4+3]+bb[j].w);
      *(ushort4*)&hid[m*CH + tx*4 + 64*j] = pk;
    }
  }
}

// ---------------- K3: dwconv3x3 + bias + exact GELU + gate-W -> hid2, ww ----------------
// 64-thr (1-wave) blocks, 8 tokens x 8 ch-groups. Register-lean: one kh-row of
// taps live at a time (3 hv + 3 wf), launch_bounds(64,4) caps VGPR<=128 so
// 4 waves/SIMD hide tap-load latency. Tap order (kh,kw) identical to before.
__global__ __launch_bounds__(64, 4) void k_dw(const unsigned short* __restrict__ hid,
    const float* __restrict__ wt_t, const float* __restrict__ dwb,
    const float* __restrict__ gww, const float* __restrict__ gwb,
    unsigned short* __restrict__ hid2, float* __restrict__ ww, int Mloc){
  const int tid = threadIdx.x;
  const int m0 = blockIdx.x*8;
  const int tl = tid>>3, cg = tid&7;
  const int m  = m0 + tl;                 // 8 consecutive tokens, same h row
  const int h = (m>>7)&127, w = m&127;
  bool ok[9];
  #pragma unroll
  for (int kh=0;kh<3;++kh)
    #pragma unroll
    for (int kw=0;kw<3;++kw)
      ok[kh*3+kw] = ((unsigned)(h+kh-1) < 128u) && ((unsigned)(w+kw-1) < 128u);

  float part[5] = {0.f,0.f,0.f,0.f,0.f};
  #pragma unroll
  for (int cc=0;cc<6;++cc){
    const int c = cg*8 + cc*64;
    float acc[8];
    {
      f8 bias = *(const f8*)&dwb[c];
      #pragma unroll
      for (int j=0;j<8;++j) acc[j] = bias[j];
    }
    #pragma unroll
    for (int kh=0;kh<3;++kh){
      us8 hv[3];
      #pragma unroll
      for (int kw=0;kw<3;++kw){
        if (ok[kh*3+kw]){
          hv[kw] = *(const us8*)&hid[(size_t)(m + (kh-1)*128 + (kw-1))*CH + c];
        } else {
          us8 z = {0,0,0,0,0,0,0,0};
          hv[kw] = z;
        }
      }
      #pragma unroll
      for (int kw=0;kw<3;++kw){
        f8 wf = *(const f8*)&wt_t[(kh*3+kw)*CH + c];
        #pragma unroll
        for (int j=0;j<8;++j)
          acc[j] = fmaf(b2f(hv[kw][j]), wf[j], acc[j]);
      }
    }
    float g[8];
    us8 ov;
    #pragma unroll
    for (int j=0;j<8;++j){
      float a = acc[j];
      g[j] = 0.5f*a*(1.f + erff(a*0.70710678118654752f));
      ov[j] = f2b(g[j]);
    }
    *(us8*)&hid2[(size_t)m*CH + c] = ov;
    #pragma unroll
    for (int s=0;s<5;++s){
      f8 gw = *(const f8*)&gww[s*CH + c];
      #pragma unroll
      for (int j=0;j<8;++j) part[s] = fmaf(g[j], gw[j], part[s]);
    }
  }
  #pragma unroll
  for (int s=0;s<5;++s){
    float v = part[s];
    v += __shfl_xor(v, 1, 64);
    v += __shfl_xor(v, 2, 64);
    v += __shfl_xor(v, 4, 64);
    part[s] = v;
  }
  if (cg==0){
    float l[5];
    #pragma unroll
    for (int s=0;s<5;++s) l[s] = part[s] + gwb[s];
    float mx = fmaxf(fmaxf(fmaxf(l[0],l[1]),fmaxf(l[2],l[3])),l[4]);
    float sum=0.f;
    #pragma unroll
    for (int s=0;s<5;++s){ l[s]=__expf(l[s]-mx); sum+=l[s]; }
    float inv=1.f/sum;
    #pragma unroll
    for (int s=0;s<5;++s) ww[(size_t)s*Mloc + m] = l[s]*inv;
  }
}

// ---------------- K4: fused W-shift-mix + fc2 via bf16 MFMA -> out (f32) ------
__global__ __launch_bounds__(256) void k_fc2(const unsigned short* __restrict__ hid2,
    const float* __restrict__ ww, const unsigned short* __restrict__ Bp,
    const float* __restrict__ fc2b, float* __restrict__ out,
    int base, int Mloc){
  __shared__ unsigned short As[64][392];   // 50176 B
  const int tid = threadIdx.x;
  const int m0 = blockIdx.x*64;
  {
    const int sr = tid>>2, sq = tid&3;
    const int ml = m0 + sr;
    const int gm = base + ml;
    const int wp = gm & 127;
    float swgt[5];
    #pragma unroll
    for (int i=0;i<5;++i){
      int w2 = wp - (i-2);
      swgt[i] = ((unsigned)w2 < 128u) ? ww[(size_t)i*Mloc + ml] : 0.f;
    }
    #pragma unroll
    for (int cc=0;cc<12;++cc){
      const int col = sq*96 + cc*8;
      float a[8] = {0.f,0.f,0.f,0.f,0.f,0.f,0.f,0.f};
      #pragma unroll
      for (int i=0;i<5;++i){
        if (swgt[i] != 0.f){
          us8 hv = *(const us8*)&hid2[(size_t)(ml-(i-2))*CH + col];
          #pragma unroll
          for (int j=0;j<8;++j) a[j] = fmaf(swgt[i], b2f(hv[j]), a[j]);
        }
      }
      us8 ov;
      #pragma unroll
      for (int j=0;j<8;++j) ov[j] = f2b(a[j]);
      *(us8*)&As[sr][col] = ov;
    }
  }
  __syncthreads();

  const int wv = tid>>6, l = tid&63;
  const int row16 = l&15, g = l>>4;
  f4v acc[6];
  #pragma unroll
  for (int nt=0;nt<6;++nt) acc[nt] = (f4v){0.f,0.f,0.f,0.f};

  #pragma unroll
  for (int ks=0;ks<12;++ks){
    s8v a = *(const s8v*)&As[wv*16 + row16][ks*32 + g*8];
    #pragma unroll
    for (int nt=0;nt<6;++nt){
      s8v b = *(const s8v*)&Bp[((size_t)(nt*12+ks)*64 + l)*8];
      acc[nt] = __builtin_amdgcn_mfma_f32_16x16x32_bf16(a, b, acc[nt], 0, 0, 0);
    }
  }

  #pragma unroll
  for (int nt=0;nt<6;++nt){
    float bias = fc2b[nt*16 + row16];
    #pragma unroll
    for (int r=0;r<4;++r){
      size_t m = (size_t)(base + m0 + wv*16 + g*4 + r);
      out[m*96 + nt*16 + row16] = acc[nt][r] + bias;
    }
  }
}

extern "C" void kernel_launch(void* const* d_in, const int* in_sizes, int n_in,
                              void* d_out, int out_size, void* d_ws, size_t ws_size,
                              hipStream_t stream) {
  const float* x     = (const float*)d_in[0];
  const float* fc1_w = (const float*)d_in[3];
  const float* fc1_b = (const float*)d_in[4];
  const float* dw_w  = (const float*)d_in[5];
  const float* dw_b  = (const float*)d_in[6];
  const float* fc2_w = (const float*)d_in[7];
  const float* fc2_b = (const float*)d_in[8];
  const float* gh_w  = (const float*)d_in[9];
  const float* gh_b  = (const float*)d_in[10];
  const float* gw_w  = (const float*)d_in[11];
  const float* gw_b  = (const float*)d_in[12];
  float* out = (float*)d_out;

  // ws layout: wt_t 9*384 f32 (13824 B) | Bp 36864 bf16 (73728 B) | chunk scratch
  float* wt_t = (float*)d_ws;
  unsigned short* Bp = (unsigned short*)((char*)d_ws + 13824);
  char*  wsc  = (char*)d_ws + 13824 + 73728;
  size_t ws_rem = (ws_size > 87552) ? ws_size - 87552 : 0;

  k_wprep<<<(9*CH + 63)/64, 64, 0, stream>>>(dw_w, wt_t);
  k_wprep2<<<144, 256, 0, stream>>>(fc2_w, Bp);

  const size_t pi = (size_t)5*Mi*4*2 + (size_t)Mi*CH*2*2;
  int NI = (int)(ws_rem / pi);
  if (NI < 1) NI = 1;
  if (NI > 16) NI = 16;

  for (int b0 = 0; b0 < 16; b0 += NI) {
    int nb = (16 - b0 < NI) ? (16 - b0) : NI;
    int Mloc = nb * Mi;
    int base = b0 * Mi;
    float* wh = (float*)wsc;
    float* ww = wh + (size_t)5*Mloc;
    unsigned short* hid  = (unsigned short*)(ww + (size_t)5*Mloc);
    unsigned short* hid2 = hid + (size_t)Mloc*CH;
    k_gate_h<<<Mloc/256, 256, 0, stream>>>(x, gh_w, gh_b, wh, base, Mloc);
    k_fc1<<<Mloc/64, 256, 0, stream>>>(x, wh, fc1_w, fc1_b, hid, base, Mloc);
    k_dw<<<Mloc/8, 64, 0, stream>>>(hid, wt_t, dw_b, gw_w, gw_b, hid2, ww, Mloc);
    k_fc2<<<Mloc/64, 256, 0, stream>>>(hid2, ww, Bp, fc2_b, out, base, Mloc);
  }
}

// Round 10
// 895.256 us; speedup vs baseline: 2.1519x; 2.1519x over previous
//
#include <hip/hip_runtime.h>
#include <cstddef>

#define Cc 96
#define CH 384
#define Mtok 262144   // B*H*W = 16*128*128
#define Mi   16384    // tokens per image

typedef unsigned short us8 __attribute__((ext_vector_type(8)));
typedef float f8 __attribute__((ext_vector_type(8)));
typedef short s8v __attribute__((ext_vector_type(8)));
typedef float f4v __attribute__((ext_vector_type(4)));

static __device__ __forceinline__ float b2f(unsigned short s){
  union { unsigned u; float f; } v; v.u = ((unsigned)s) << 16; return v.f;
}
static __device__ __forceinline__ unsigned short f2b(float f){
  union { float f; unsigned u; } v; v.f = f;
  unsigned r = v.u + 0x7fffu + ((v.u >> 16) & 1u);
  return (unsigned short)(r >> 16);
}

// ---------------- K0a: transpose dw_w [c][tap] -> wt_t [tap][c] ----------------
__global__ __launch_bounds__(64) void k_wprep(const float* __restrict__ dww,
    float* __restrict__ wt_t){
  int i = blockIdx.x*64 + threadIdx.x;   // i = tap*CH + c
  if (i < 9*CH){
    int tap = i / CH, c = i - tap*CH;
    wt_t[i] = dww[c*9 + tap];
  }
}

// ---------------- K0b: pack fc2_w [384][96] f32 -> bf16 MFMA b-frag layout ----
__global__ __launch_bounds__(256) void k_wprep2(const float* __restrict__ fc2w,
    unsigned short* __restrict__ Bp){
  int i = blockIdx.x*256 + threadIdx.x;   // < 6*12*64*8 = 36864
  int j = i & 7;
  int t = i >> 3;
  int l = t & 63;
  int u = t >> 6;          // 0..71
  int ks = u % 12, nt = u / 12;
  int k   = ks*32 + (l>>4)*8 + j;
  int col = nt*16 + (l&15);
  Bp[i] = f2b(fc2w[(size_t)k*96 + col]);
}

// ---------------- K1: gate-H softmax weights  wh[5][Mloc] ----------------
__global__ __launch_bounds__(256) void k_gate_h(const float* __restrict__ x,
    const float* __restrict__ gh_w, const float* __restrict__ gh_b,
    float* __restrict__ wh, int base, int Mloc){
  int m = blockIdx.x*256 + threadIdx.x;
  const float* xr = x + (size_t)(base + m)*Cc;
  float l[5];
  #pragma unroll
  for (int s=0;s<5;++s) l[s] = gh_b[s];
  #pragma unroll
  for (int c=0;c<Cc;c+=4){
    float4 xv = *(const float4*)(xr+c);
    #pragma unroll
    for (int s=0;s<5;++s){
      float4 g = *(const float4*)(gh_w + s*Cc + c);
      l[s]=fmaf(xv.x,g.x,l[s]); l[s]=fmaf(xv.y,g.y,l[s]);
      l[s]=fmaf(xv.z,g.z,l[s]); l[s]=fmaf(xv.w,g.w,l[s]);
    }
  }
  float mx = fmaxf(fmaxf(fmaxf(l[0],l[1]),fmaxf(l[2],l[3])),l[4]);
  float sum=0.f;
  #pragma unroll
  for (int s=0;s<5;++s){ l[s]=__expf(l[s]-mx); sum+=l[s]; }
  float inv = 1.f/sum;
  #pragma unroll
  for (int s=0;s<5;++s) wh[(size_t)s*Mloc + m] = l[s]*inv;
}

// ---------------- K2: fused H-shift-mix + fc1 GEMM -> hid (bf16) ----------------
__global__ __launch_bounds__(256) void k_fc1(const float* __restrict__ x,
    const float* __restrict__ wh, const float* __restrict__ fc1w,
    const float* __restrict__ fc1b, unsigned short* __restrict__ hid,
    int base, int Mloc){
  __shared__ float As[64][100];
  __shared__ float Bs[16*CH];     // one 16-row K-chunk of fc1w, flat
  const int tid = threadIdx.x;
  const int nwg = gridDim.x;
  const int cpx = nwg >> 3;
  const int bid = (int)blockIdx.x;
  const int wg  = (bid & 7)*cpx + (bid >> 3);
  const int m0 = wg*64;
  {
    int sr = tid>>2, sq = tid&3;
    int ml = m0 + sr;              // local token
    int gm = base + ml;            // global token
    int sh = (gm>>7)&127;          // h coordinate
    float swgt[5];
    #pragma unroll
    for (int i=0;i<5;++i){
      int h2 = sh - (i-2);
      swgt[i] = ((unsigned)h2 < 128u) ? wh[(size_t)i*Mloc + ml] : 0.f;
    }
    #pragma unroll
    for (int j=0;j<6;++j){
      int c = sq*24 + j*4;
      float4 a = make_float4(0.f,0.f,0.f,0.f);
      #pragma unroll
      for (int i=0;i<5;++i){
        if (swgt[i] != 0.f){
          float4 xv = *(const float4*)&x[(size_t)(gm - (i-2)*128)*Cc + c];
          a.x=fmaf(swgt[i],xv.x,a.x); a.y=fmaf(swgt[i],xv.y,a.y);
          a.z=fmaf(swgt[i],xv.z,a.z); a.w=fmaf(swgt[i],xv.w,a.w);
        }
      }
      *(float4*)&As[sr][c] = a;
    }
  }
  const int tx = tid&15, ty = tid>>4;
  float acc[4][24];
  #pragma unroll
  for (int i=0;i<4;++i)
    #pragma unroll
    for (int j=0;j<24;++j) acc[i][j] = 0.f;

  for (int kc=0;kc<6;++kc){
    const float4* src = (const float4*)(fc1w + (size_t)kc*16*CH);
    float4* dst = (float4*)Bs;
    #pragma unroll
    for (int p=0;p<6;++p) dst[tid + p*256] = src[tid + p*256];
    __syncthreads();
    #pragma unroll
    for (int q=0;q<4;++q){
      float4 av[4];
      #pragma unroll
      for (int i=0;i<4;++i) av[i] = *(const float4*)&As[ty*4+i][kc*16 + q*4];
      #pragma unroll
      for (int kk=0;kk<4;++kk){
        float4 bv[6];
        #pragma unroll
        for (int j=0;j<6;++j) bv[j] = *(const float4*)&Bs[(q*4+kk)*CH + tx*4 + 64*j];
        #pragma unroll
        for (int i=0;i<4;++i){
          float a = (kk==0)?av[i].x:(kk==1)?av[i].y:(kk==2)?av[i].z:av[i].w;
          #pragma unroll
          for (int j=0;j<6;++j){
            acc[i][j*4+0]=fmaf(a,bv[j].x,acc[i][j*4+0]);
            acc[i][j*4+1]=fmaf(a,bv[j].y,acc[i][j*4+1]);
            acc[i][j*4+2]=fmaf(a,bv[j].z,acc[i][j*4+2]);
            acc[i][j*4+3]=fmaf(a,bv[j].w,acc[i][j*4+3]);
          }
        }
      }
    }
    __syncthreads();
  }
  float4 bb[6];
  #pragma unroll
  for (int j=0;j<6;++j) bb[j] = *(const float4*)&fc1b[tx*4 + 64*j];
  #pragma unroll
  for (int i=0;i<4;++i){
    size_t m = (size_t)(m0 + ty*4 + i);
    #pragma unroll
    for (int j=0;j<6;++j){
      ushort4 pk;
      pk.x = f2b(acc[i][j*4+0]+bb[j].x);
      pk.y = f2b(acc[i][j*4+1]+bb[j].y);
      pk.z = f2b(acc[i][j*4+2]+bb[j].z);
      pk.w = f2b(acc[i][j*4+3]+bb[j].w);
      *(ushort4*)&hid[m*CH + tx*4 + 64*j] = pk;
    }
  }
}

// ---------------- K3: dwconv3x3 + bias + exact GELU + gate-W -> hid2, ww ----------------
// 64-thr (1-wave) blocks, 8 tokens x 8 ch-groups. Row-wise taps (3 live) and
// cc-loop NOT unrolled (unroll 1) to bound register liveness WITHOUT a forced
// launch_bounds cap (the (64,4) cap caused 3GB of spill traffic — never force).
__global__ __launch_bounds__(64) void k_dw(const unsigned short* __restrict__ hid,
    const float* __restrict__ wt_t, const float* __restrict__ dwb,
    const float* __restrict__ gww, const float* __restrict__ gwb,
    unsigned short* __restrict__ hid2, float* __restrict__ ww, int Mloc){
  const int tid = threadIdx.x;
  const int m0 = blockIdx.x*8;
  const int tl = tid>>3, cg = tid&7;
  const int m  = m0 + tl;                 // 8 consecutive tokens, same h row
  const int h = (m>>7)&127, w = m&127;
  bool ok[9];
  #pragma unroll
  for (int kh=0;kh<3;++kh)
    #pragma unroll
    for (int kw=0;kw<3;++kw)
      ok[kh*3+kw] = ((unsigned)(h+kh-1) < 128u) && ((unsigned)(w+kw-1) < 128u);

  float part[5] = {0.f,0.f,0.f,0.f,0.f};
  #pragma unroll 1
  for (int cc=0;cc<6;++cc){
    const int c = cg*8 + cc*64;
    float acc[8];
    {
      f8 bias = *(const f8*)&dwb[c];
      #pragma unroll
      for (int j=0;j<8;++j) acc[j] = bias[j];
    }
    #pragma unroll
    for (int kh=0;kh<3;++kh){
      us8 hv[3];
      #pragma unroll
      for (int kw=0;kw<3;++kw){
        if (ok[kh*3+kw]){
          hv[kw] = *(const us8*)&hid[(size_t)(m + (kh-1)*128 + (kw-1))*CH + c];
        } else {
          us8 z = {0,0,0,0,0,0,0,0};
          hv[kw] = z;
        }
      }
      #pragma unroll
      for (int kw=0;kw<3;++kw){
        f8 wf = *(const f8*)&wt_t[(kh*3+kw)*CH + c];
        #pragma unroll
        for (int j=0;j<8;++j)
          acc[j] = fmaf(b2f(hv[kw][j]), wf[j], acc[j]);
      }
    }
    float g[8];
    us8 ov;
    #pragma unroll
    for (int j=0;j<8;++j){
      float a = acc[j];
      g[j] = 0.5f*a*(1.f + erff(a*0.70710678118654752f));
      ov[j] = f2b(g[j]);
    }
    *(us8*)&hid2[(size_t)m*CH + c] = ov;
    #pragma unroll
    for (int s=0;s<5;++s){
      f8 gw = *(const f8*)&gww[s*CH + c];
      #pragma unroll
      for (int j=0;j<8;++j) part[s] = fmaf(g[j], gw[j], part[s]);
    }
  }
  #pragma unroll
  for (int s=0;s<5;++s){
    float v = part[s];
    v += __shfl_xor(v, 1, 64);
    v += __shfl_xor(v, 2, 64);
    v += __shfl_xor(v, 4, 64);
    part[s] = v;
  }
  if (cg==0){
    float l[5];
    #pragma unroll
    for (int s=0;s<5;++s) l[s] = part[s] + gwb[s];
    float mx = fmaxf(fmaxf(fmaxf(l[0],l[1]),fmaxf(l[2],l[3])),l[4]);
    float sum=0.f;
    #pragma unroll
    for (int s=0;s<5;++s){ l[s]=__expf(l[s]-mx); sum+=l[s]; }
    float inv=1.f/sum;
    #pragma unroll
    for (int s=0;s<5;++s) ww[(size_t)s*Mloc + m] = l[s]*inv;
  }
}

// ---------------- K4: fused W-shift-mix + fc2 via bf16 MFMA -> out (f32) ------
__global__ __launch_bounds__(256) void k_fc2(const unsigned short* __restrict__ hid2,
    const float* __restrict__ ww, const unsigned short* __restrict__ Bp,
    const float* __restrict__ fc2b, float* __restrict__ out,
    int base, int Mloc){
  __shared__ unsigned short As[64][392];   // 50176 B
  const int tid = threadIdx.x;
  const int m0 = blockIdx.x*64;
  {
    const int sr = tid>>2, sq = tid&3;
    const int ml = m0 + sr;
    const int gm = base + ml;
    const int wp = gm & 127;
    float swgt[5];
    #pragma unroll
    for (int i=0;i<5;++i){
      int w2 = wp - (i-2);
      swgt[i] = ((unsigned)w2 < 128u) ? ww[(size_t)i*Mloc + ml] : 0.f;
    }
    #pragma unroll
    for (int cc=0;cc<12;++cc){
      const int col = sq*96 + cc*8;
      float a[8] = {0.f,0.f,0.f,0.f,0.f,0.f,0.f,0.f};
      #pragma unroll
      for (int i=0;i<5;++i){
        if (swgt[i] != 0.f){
          us8 hv = *(const us8*)&hid2[(size_t)(ml-(i-2))*CH + col];
          #pragma unroll
          for (int j=0;j<8;++j) a[j] = fmaf(swgt[i], b2f(hv[j]), a[j]);
        }
      }
      us8 ov;
      #pragma unroll
      for (int j=0;j<8;++j) ov[j] = f2b(a[j]);
      *(us8*)&As[sr][col] = ov;
    }
  }
  __syncthreads();

  const int wv = tid>>6, l = tid&63;
  const int row16 = l&15, g = l>>4;
  f4v acc[6];
  #pragma unroll
  for (int nt=0;nt<6;++nt) acc[nt] = (f4v){0.f,0.f,0.f,0.f};

  #pragma unroll
  for (int ks=0;ks<12;++ks){
    s8v a = *(const s8v*)&As[wv*16 + row16][ks*32 + g*8];
    #pragma unroll
    for (int nt=0;nt<6;++nt){
      s8v b = *(const s8v*)&Bp[((size_t)(nt*12+ks)*64 + l)*8];
      acc[nt] = __builtin_amdgcn_mfma_f32_16x16x32_bf16(a, b, acc[nt], 0, 0, 0);
    }
  }

  #pragma unroll
  for (int nt=0;nt<6;++nt){
    float bias = fc2b[nt*16 + row16];
    #pragma unroll
    for (int r=0;r<4;++r){
      size_t m = (size_t)(base + m0 + wv*16 + g*4 + r);
      out[m*96 + nt*16 + row16] = acc[nt][r] + bias;
    }
  }
}

extern "C" void kernel_launch(void* const* d_in, const int* in_sizes, int n_in,
                              void* d_out, int out_size, void* d_ws, size_t ws_size,
                              hipStream_t stream) {
  const float* x     = (const float*)d_in[0];
  const float* fc1_w = (const float*)d_in[3];
  const float* fc1_b = (const float*)d_in[4];
  const float* dw_w  = (const float*)d_in[5];
  const float* dw_b  = (const float*)d_in[6];
  const float* fc2_w = (const float*)d_in[7];
  const float* fc2_b = (const float*)d_in[8];
  const float* gh_w  = (const float*)d_in[9];
  const float* gh_b  = (const float*)d_in[10];
  const float* gw_w  = (const float*)d_in[11];
  const float* gw_b  = (const float*)d_in[12];
  float* out = (float*)d_out;

  // ws layout: wt_t 9*384 f32 (13824 B) | Bp 36864 bf16 (73728 B) | chunk scratch
  float* wt_t = (float*)d_ws;
  unsigned short* Bp = (unsigned short*)((char*)d_ws + 13824);
  char*  wsc  = (char*)d_ws + 13824 + 73728;
  size_t ws_rem = (ws_size > 87552) ? ws_size - 87552 : 0;

  k_wprep<<<(9*CH + 63)/64, 64, 0, stream>>>(dw_w, wt_t);
  k_wprep2<<<144, 256, 0, stream>>>(fc2_w, Bp);

  const size_t pi = (size_t)5*Mi*4*2 + (size_t)Mi*CH*2*2;
  int NI = (int)(ws_rem / pi);
  if (NI < 1) NI = 1;
  if (NI > 16) NI = 16;

  for (int b0 = 0; b0 < 16; b0 += NI) {
    int nb = (16 - b0 < NI) ? (16 - b0) : NI;
    int Mloc = nb * Mi;
    int base = b0 * Mi;
    float* wh = (float*)wsc;
    float* ww = wh + (size_t)5*Mloc;
    unsigned short* hid  = (unsigned short*)(ww + (size_t)5*Mloc);
    unsigned short* hid2 = hid + (size_t)Mloc*CH;
    k_gate_h<<<Mloc/256, 256, 0, stream>>>(x, gh_w, gh_b, wh, base, Mloc);
    k_fc1<<<Mloc/64, 256, 0, stream>>>(x, wh, fc1_w, fc1_b, hid, base, Mloc);
    k_dw<<<Mloc/8, 64, 0, stream>>>(hid, wt_t, dw_b, gw_w, gw_b, hid2, ww, Mloc);
    k_fc2<<<Mloc/64, 256, 0, stream>>>(hid2, ww, Bp, fc2_b, out, base, Mloc);
  }
}

// Round 11
// 715.765 us; speedup vs baseline: 2.6915x; 1.2508x over previous
//
#include <hip/hip_runtime.h>
#include <cstddef>

#define Cc 96
#define CH 384
#define Mtok 262144   // B*H*W = 16*128*128
#define Mi   16384    // tokens per image

typedef unsigned short us8 __attribute__((ext_vector_type(8)));
typedef float f8 __attribute__((ext_vector_type(8)));
typedef short s8v __attribute__((ext_vector_type(8)));
typedef float f4v __attribute__((ext_vector_type(4)));

static __device__ __forceinline__ float b2f(unsigned short s){
  union { unsigned u; float f; } v; v.u = ((unsigned)s) << 16; return v.f;
}
static __device__ __forceinline__ unsigned short f2b(float f){
  union { float f; unsigned u; } v; v.f = f;
  unsigned r = v.u + 0x7fffu + ((v.u >> 16) & 1u);
  return (unsigned short)(r >> 16);
}

// ---------------- K0a: transpose dw_w [c][tap] -> wt_t [tap][c] ----------------
__global__ __launch_bounds__(64) void k_wprep(const float* __restrict__ dww,
    float* __restrict__ wt_t){
  int i = blockIdx.x*64 + threadIdx.x;   // i = tap*CH + c
  if (i < 9*CH){
    int tap = i / CH, c = i - tap*CH;
    wt_t[i] = dww[c*9 + tap];
  }
}

// ---------------- K0b: pack fc2_w [384][96] f32 -> bf16 MFMA b-frag layout ----
__global__ __launch_bounds__(256) void k_wprep2(const float* __restrict__ fc2w,
    unsigned short* __restrict__ Bp){
  int i = blockIdx.x*256 + threadIdx.x;   // < 6*12*64*8 = 36864
  int j = i & 7;
  int t = i >> 3;
  int l = t & 63;
  int u = t >> 6;          // 0..71
  int ks = u % 12, nt = u / 12;
  int k   = ks*32 + (l>>4)*8 + j;
  int col = nt*16 + (l&15);
  Bp[i] = f2b(fc2w[(size_t)k*96 + col]);
}

// ---------------- K1: gate-H softmax weights  wh[5][Mloc] ----------------
__global__ __launch_bounds__(256) void k_gate_h(const float* __restrict__ x,
    const float* __restrict__ gh_w, const float* __restrict__ gh_b,
    float* __restrict__ wh, int base, int Mloc){
  int m = blockIdx.x*256 + threadIdx.x;
  const float* xr = x + (size_t)(base + m)*Cc;
  float l[5];
  #pragma unroll
  for (int s=0;s<5;++s) l[s] = gh_b[s];
  #pragma unroll
  for (int c=0;c<Cc;c+=4){
    float4 xv = *(const float4*)(xr+c);
    #pragma unroll
    for (int s=0;s<5;++s){
      float4 g = *(const float4*)(gh_w + s*Cc + c);
      l[s]=fmaf(xv.x,g.x,l[s]); l[s]=fmaf(xv.y,g.y,l[s]);
      l[s]=fmaf(xv.z,g.z,l[s]); l[s]=fmaf(xv.w,g.w,l[s]);
    }
  }
  float mx = fmaxf(fmaxf(fmaxf(l[0],l[1]),fmaxf(l[2],l[3])),l[4]);
  float sum=0.f;
  #pragma unroll
  for (int s=0;s<5;++s){ l[s]=__expf(l[s]-mx); sum+=l[s]; }
  float inv = 1.f/sum;
  #pragma unroll
  for (int s=0;s<5;++s) wh[(size_t)s*Mloc + m] = l[s]*inv;
}

// ---------------- K2: fused H-shift-mix + fc1 GEMM -> hid (bf16) ----------------
__global__ __launch_bounds__(256) void k_fc1(const float* __restrict__ x,
    const float* __restrict__ wh, const float* __restrict__ fc1w,
    const float* __restrict__ fc1b, unsigned short* __restrict__ hid,
    int base, int Mloc){
  __shared__ float As[64][100];
  __shared__ float Bs[16*CH];     // one 16-row K-chunk of fc1w, flat
  const int tid = threadIdx.x;
  const int nwg = gridDim.x;
  const int cpx = nwg >> 3;
  const int bid = (int)blockIdx.x;
  const int wg  = (bid & 7)*cpx + (bid >> 3);
  const int m0 = wg*64;
  {
    int sr = tid>>2, sq = tid&3;
    int ml = m0 + sr;              // local token
    int gm = base + ml;            // global token
    int sh = (gm>>7)&127;          // h coordinate
    float swgt[5];
    #pragma unroll
    for (int i=0;i<5;++i){
      int h2 = sh - (i-2);
      swgt[i] = ((unsigned)h2 < 128u) ? wh[(size_t)i*Mloc + ml] : 0.f;
    }
    #pragma unroll
    for (int j=0;j<6;++j){
      int c = sq*24 + j*4;
      float4 a = make_float4(0.f,0.f,0.f,0.f);
      #pragma unroll
      for (int i=0;i<5;++i){
        if (swgt[i] != 0.f){
          float4 xv = *(const float4*)&x[(size_t)(gm - (i-2)*128)*Cc + c];
          a.x=fmaf(swgt[i],xv.x,a.x); a.y=fmaf(swgt[i],xv.y,a.y);
          a.z=fmaf(swgt[i],xv.z,a.z); a.w=fmaf(swgt[i],xv.w,a.w);
        }
      }
      *(float4*)&As[sr][c] = a;
    }
  }
  const int tx = tid&15, ty = tid>>4;
  float acc[4][24];
  #pragma unroll
  for (int i=0;i<4;++i)
    #pragma unroll
    for (int j=0;j<24;++j) acc[i][j] = 0.f;

  for (int kc=0;kc<6;++kc){
    const float4* src = (const float4*)(fc1w + (size_t)kc*16*CH);
    float4* dst = (float4*)Bs;
    #pragma unroll
    for (int p=0;p<6;++p) dst[tid + p*256] = src[tid + p*256];
    __syncthreads();
    #pragma unroll
    for (int q=0;q<4;++q){
      float4 av[4];
      #pragma unroll
      for (int i=0;i<4;++i) av[i] = *(const float4*)&As[ty*4+i][kc*16 + q*4];
      #pragma unroll
      for (int kk=0;kk<4;++kk){
        float4 bv[6];
        #pragma unroll
        for (int j=0;j<6;++j) bv[j] = *(const float4*)&Bs[(q*4+kk)*CH + tx*4 + 64*j];
        #pragma unroll
        for (int i=0;i<4;++i){
          float a = (kk==0)?av[i].x:(kk==1)?av[i].y:(kk==2)?av[i].z:av[i].w;
          #pragma unroll
          for (int j=0;j<6;++j){
            acc[i][j*4+0]=fmaf(a,bv[j].x,acc[i][j*4+0]);
            acc[i][j*4+1]=fmaf(a,bv[j].y,acc[i][j*4+1]);
            acc[i][j*4+2]=fmaf(a,bv[j].z,acc[i][j*4+2]);
            acc[i][j*4+3]=fmaf(a,bv[j].w,acc[i][j*4+3]);
          }
        }
      }
    }
    __syncthreads();
  }
  float4 bb[6];
  #pragma unroll
  for (int j=0;j<6;++j) bb[j] = *(const float4*)&fc1b[tx*4 + 64*j];
  #pragma unroll
  for (int i=0;i<4;++i){
    size_t m = (size_t)(m0 + ty*4 + i);
    #pragma unroll
    for (int j=0;j<6;++j){
      ushort4 pk;
      pk.x = f2b(acc[i][j*4+0]+bb[j].x);
      pk.y = f2b(acc[i][j*4+1]+bb[j].y);
      pk.z = f2b(acc[i][j*4+2]+bb[j].z);
      pk.w = f2b(acc[i][j*4+3]+bb[j].w);
      *(ushort4*)&hid[m*CH + tx*4 + 64*j] = pk;
    }
  }
}

// ---------------- K3: dwconv3x3 + bias + exact GELU + gate-W -> hid2, ww ----------------
__global__ __launch_bounds__(64) void k_dw(const unsigned short* __restrict__ hid,
    const float* __restrict__ wt_t, const float* __restrict__ dwb,
    const float* __restrict__ gww, const float* __restrict__ gwb,
    unsigned short* __restrict__ hid2, float* __restrict__ ww, int Mloc){
  const int tid = threadIdx.x;
  const int m0 = blockIdx.x*8;
  const int tl = tid>>3, cg = tid&7;
  const int m  = m0 + tl;                 // 8 consecutive tokens, same h row
  const int h = (m>>7)&127, w = m&127;
  bool ok[9];
  #pragma unroll
  for (int kh=0;kh<3;++kh)
    #pragma unroll
    for (int kw=0;kw<3;++kw)
      ok[kh*3+kw] = ((unsigned)(h+kh-1) < 128u) && ((unsigned)(w+kw-1) < 128u);

  float part[5] = {0.f,0.f,0.f,0.f,0.f};
  #pragma unroll 1
  for (int cc=0;cc<6;++cc){
    const int c = cg*8 + cc*64;
    float acc[8];
    {
      f8 bias = *(const f8*)&dwb[c];
      #pragma unroll
      for (int j=0;j<8;++j) acc[j] = bias[j];
    }
    #pragma unroll
    for (int kh=0;kh<3;++kh){
      us8 hv[3];
      #pragma unroll
      for (int kw=0;kw<3;++kw){
        if (ok[kh*3+kw]){
          hv[kw] = *(const us8*)&hid[(size_t)(m + (kh-1)*128 + (kw-1))*CH + c];
        } else {
          us8 z = {0,0,0,0,0,0,0,0};
          hv[kw] = z;
        }
      }
      #pragma unroll
      for (int kw=0;kw<3;++kw){
        f8 wf = *(const f8*)&wt_t[(kh*3+kw)*CH + c];
        #pragma unroll
        for (int j=0;j<8;++j)
          acc[j] = fmaf(b2f(hv[kw][j]), wf[j], acc[j]);
      }
    }
    float g[8];
    us8 ov;
    #pragma unroll
    for (int j=0;j<8;++j){
      float a = acc[j];
      g[j] = 0.5f*a*(1.f + erff(a*0.70710678118654752f));
      ov[j] = f2b(g[j]);
    }
    *(us8*)&hid2[(size_t)m*CH + c] = ov;
    #pragma unroll
    for (int s=0;s<5;++s){
      f8 gw = *(const f8*)&gww[s*CH + c];
      #pragma unroll
      for (int j=0;j<8;++j) part[s] = fmaf(g[j], gw[j], part[s]);
    }
  }
  #pragma unroll
  for (int s=0;s<5;++s){
    float v = part[s];
    v += __shfl_xor(v, 1, 64);
    v += __shfl_xor(v, 2, 64);
    v += __shfl_xor(v, 4, 64);
    part[s] = v;
  }
  if (cg==0){
    float l[5];
    #pragma unroll
    for (int s=0;s<5;++s) l[s] = part[s] + gwb[s];
    float mx = fmaxf(fmaxf(fmaxf(l[0],l[1]),fmaxf(l[2],l[3])),l[4]);
    float sum=0.f;
    #pragma unroll
    for (int s=0;s<5;++s){ l[s]=__expf(l[s]-mx); sum+=l[s]; }
    float inv=1.f/sum;
    #pragma unroll
    for (int s=0;s<5;++s) ww[(size_t)s*Mloc + m] = l[s]*inv;
  }
}

// ---------------- K4: PURE fc2 GEMM via bf16 MFMA: y = hid2 @ fc2w (bf16) -----
// Linearity: W-shift mix commutes with the GEMM, so no mix here — straight
// coalesced staging (1x traffic instead of 5x gathers). Bias applied in blend.
__global__ __launch_bounds__(256) void k_fc2(const unsigned short* __restrict__ hid2,
    const unsigned short* __restrict__ Bp, unsigned short* __restrict__ y,
    int Mloc){
  __shared__ unsigned short As[64][392];   // 50176 B
  const int tid = threadIdx.x;
  const int m0 = blockIdx.x*64;
  {
    const int sr = tid>>2, sq = tid&3;
    const unsigned short* src = &hid2[(size_t)(m0+sr)*CH + sq*96];
    #pragma unroll
    for (int cc=0;cc<12;++cc)
      *(us8*)&As[sr][sq*96 + cc*8] = *(const us8*)&src[cc*8];
  }
  __syncthreads();

  const int wv = tid>>6, l = tid&63;
  const int row16 = l&15, g = l>>4;
  f4v acc[6];
  #pragma unroll
  for (int nt=0;nt<6;++nt) acc[nt] = (f4v){0.f,0.f,0.f,0.f};

  #pragma unroll
  for (int ks=0;ks<12;++ks){
    s8v a = *(const s8v*)&As[wv*16 + row16][ks*32 + g*8];
    #pragma unroll
    for (int nt=0;nt<6;++nt){
      s8v b = *(const s8v*)&Bp[((size_t)(nt*12+ks)*64 + l)*8];
      acc[nt] = __builtin_amdgcn_mfma_f32_16x16x32_bf16(a, b, acc[nt], 0, 0, 0);
    }
  }

  #pragma unroll
  for (int nt=0;nt<6;++nt){
    #pragma unroll
    for (int r=0;r<4;++r){
      size_t m = (size_t)(m0 + wv*16 + g*4 + r);
      y[m*96 + nt*16 + row16] = f2b(acc[nt][r]);
    }
  }
}

// ---------------- K5: W-shift blend: out[m] = sum_i ww[i][m]*y[m-(i-2)] + b ---
__global__ __launch_bounds__(256) void k_blend(const unsigned short* __restrict__ y,
    const float* __restrict__ ww, const float* __restrict__ fc2b,
    float* __restrict__ out, int base, int Mloc){
  const int tid = threadIdx.x;
  const int m0 = blockIdx.x*64;
  const int tl = tid>>2, q = tid&3;   // token, 24-col quarter
  const int ml = m0 + tl;
  const int gm = base + ml;
  const int wp = gm & 127;
  float swgt[5];
  #pragma unroll
  for (int i=0;i<5;++i){
    int w2 = wp - (i-2);
    swgt[i] = ((unsigned)w2 < 128u) ? ww[(size_t)i*Mloc + ml] : 0.f;
  }
  const int c0 = q*24;
  float acc[24];
  #pragma unroll
  for (int j=0;j<24;++j) acc[j] = fc2b[c0+j];
  #pragma unroll
  for (int i=0;i<5;++i){
    if (swgt[i] != 0.f){
      const unsigned short* yr = &y[(size_t)(ml-(i-2))*96 + c0];
      #pragma unroll
      for (int p=0;p<3;++p){
        us8 v = *(const us8*)&yr[p*8];
        #pragma unroll
        for (int j=0;j<8;++j) acc[p*8+j] = fmaf(swgt[i], b2f(v[j]), acc[p*8+j]);
      }
    }
  }
  float* o = &out[(size_t)gm*96 + c0];
  #pragma unroll
  for (int p=0;p<6;++p)
    *(float4*)&o[p*4] = make_float4(acc[p*4],acc[p*4+1],acc[p*4+2],acc[p*4+3]);
}

extern "C" void kernel_launch(void* const* d_in, const int* in_sizes, int n_in,
                              void* d_out, int out_size, void* d_ws, size_t ws_size,
                              hipStream_t stream) {
  const float* x     = (const float*)d_in[0];
  const float* fc1_w = (const float*)d_in[3];
  const float* fc1_b = (const float*)d_in[4];
  const float* dw_w  = (const float*)d_in[5];
  const float* dw_b  = (const float*)d_in[6];
  const float* fc2_w = (const float*)d_in[7];
  const float* fc2_b = (const float*)d_in[8];
  const float* gh_w  = (const float*)d_in[9];
  const float* gh_b  = (const float*)d_in[10];
  const float* gw_w  = (const float*)d_in[11];
  const float* gw_b  = (const float*)d_in[12];
  float* out = (float*)d_out;

  // ws layout: wt_t 9*384 f32 (13824 B) | Bp 36864 bf16 (73728 B) | chunk scratch
  float* wt_t = (float*)d_ws;
  unsigned short* Bp = (unsigned short*)((char*)d_ws + 13824);
  char*  wsc  = (char*)d_ws + 13824 + 73728;
  size_t ws_rem = (ws_size > 87552) ? ws_size - 87552 : 0;

  k_wprep<<<(9*CH + 63)/64, 64, 0, stream>>>(dw_w, wt_t);
  k_wprep2<<<144, 256, 0, stream>>>(fc2_w, Bp);

  // per-image: wh+ww 5*Mi*4*2 | hid+hid2 Mi*384*2*2 | y Mi*96*2
  const size_t pi = (size_t)5*Mi*4*2 + (size_t)Mi*CH*2*2 + (size_t)Mi*96*2;
  int NI = (int)(ws_rem / pi);
  if (NI < 1) NI = 1;
  if (NI > 16) NI = 16;

  for (int b0 = 0; b0 < 16; b0 += NI) {
    int nb = (16 - b0 < NI) ? (16 - b0) : NI;
    int Mloc = nb * Mi;
    int base = b0 * Mi;
    float* wh = (float*)wsc;
    float* ww = wh + (size_t)5*Mloc;
    unsigned short* hid  = (unsigned short*)(ww + (size_t)5*Mloc);
    unsigned short* hid2 = hid + (size_t)Mloc*CH;
    unsigned short* yb   = hid2 + (size_t)Mloc*CH;
    k_gate_h<<<Mloc/256, 256, 0, stream>>>(x, gh_w, gh_b, wh, base, Mloc);
    k_fc1<<<Mloc/64, 256, 0, stream>>>(x, wh, fc1_w, fc1_b, hid, base, Mloc);
    k_dw<<<Mloc/8, 64, 0, stream>>>(hid, wt_t, dw_b, gw_w, gw_b, hid2, ww, Mloc);
    k_fc2<<<Mloc/64, 256, 0, stream>>>(hid2, Bp, yb, Mloc);
    k_blend<<<Mloc/64, 256, 0, stream>>>(yb, ww, fc2_b, out, base, Mloc);
  }
}

// Round 12
// 676.414 us; speedup vs baseline: 2.8481x; 1.0582x over previous
//
#include <hip/hip_runtime.h>
#include <cstddef>

#define Cc 96
#define CH 384
#define Mtok 262144   // B*H*W = 16*128*128
#define Mi   16384    // tokens per image

typedef unsigned short us8 __attribute__((ext_vector_type(8)));
typedef float f8 __attribute__((ext_vector_type(8)));
typedef short s8v __attribute__((ext_vector_type(8)));
typedef float f4v __attribute__((ext_vector_type(4)));

static __device__ __forceinline__ float b2f(unsigned short s){
  union { unsigned u; float f; } v; v.u = ((unsigned)s) << 16; return v.f;
}
static __device__ __forceinline__ unsigned short f2b(float f){
  union { float f; unsigned u; } v; v.f = f;
  unsigned r = v.u + 0x7fffu + ((v.u >> 16) & 1u);
  return (unsigned short)(r >> 16);
}

// ---------------- K0a: transpose dw_w [c][tap] -> wt_t [tap][c] ----------------
__global__ __launch_bounds__(64) void k_wprep(const float* __restrict__ dww,
    float* __restrict__ wt_t){
  int i = blockIdx.x*64 + threadIdx.x;   // i = tap*CH + c
  if (i < 9*CH){
    int tap = i / CH, c = i - tap*CH;
    wt_t[i] = dww[c*9 + tap];
  }
}

// ---------------- K0b: pack fc2_w [384][96] f32 -> bf16 MFMA b-frag layout ----
__global__ __launch_bounds__(256) void k_wprep2(const float* __restrict__ fc2w,
    unsigned short* __restrict__ Bp){
  int i = blockIdx.x*256 + threadIdx.x;   // < 6*12*64*8 = 36864
  int j = i & 7;
  int t = i >> 3;
  int l = t & 63;
  int u = t >> 6;          // 0..71
  int ks = u % 12, nt = u / 12;
  int k   = ks*32 + (l>>4)*8 + j;
  int col = nt*16 + (l&15);
  Bp[i] = f2b(fc2w[(size_t)k*96 + col]);
}

// ---------------- K0c: pack fc1_w [96][384] f32 -> bf16 MFMA b-frag layout ----
// Bp1[((nt*3+ks)*64 + l)*8 + j] = bf16( fc1w[(ks*32+(l>>4)*8+j)*384 + nt*16+(l&15)] )
__global__ __launch_bounds__(256) void k_wprep1(const float* __restrict__ fc1w,
    unsigned short* __restrict__ Bp1){
  int i = blockIdx.x*256 + threadIdx.x;   // < 24*3*64*8 = 36864
  int j = i & 7;
  int t = i >> 3;
  int l = t & 63;
  int u = t >> 6;          // 0..71
  int ks = u % 3, nt = u / 3;
  int k   = ks*32 + (l>>4)*8 + j;
  int col = nt*16 + (l&15);
  Bp1[i] = f2b(fc1w[(size_t)k*CH + col]);
}

// ---------------- K1: gate-H softmax weights  wh[5][Mloc] ----------------
__global__ __launch_bounds__(256) void k_gate_h(const float* __restrict__ x,
    const float* __restrict__ gh_w, const float* __restrict__ gh_b,
    float* __restrict__ wh, int base, int Mloc){
  int m = blockIdx.x*256 + threadIdx.x;
  const float* xr = x + (size_t)(base + m)*Cc;
  float l[5];
  #pragma unroll
  for (int s=0;s<5;++s) l[s] = gh_b[s];
  #pragma unroll
  for (int c=0;c<Cc;c+=4){
    float4 xv = *(const float4*)(xr+c);
    #pragma unroll
    for (int s=0;s<5;++s){
      float4 g = *(const float4*)(gh_w + s*Cc + c);
      l[s]=fmaf(xv.x,g.x,l[s]); l[s]=fmaf(xv.y,g.y,l[s]);
      l[s]=fmaf(xv.z,g.z,l[s]); l[s]=fmaf(xv.w,g.w,l[s]);
    }
  }
  float mx = fmaxf(fmaxf(fmaxf(l[0],l[1]),fmaxf(l[2],l[3])),l[4]);
  float sum=0.f;
  #pragma unroll
  for (int s=0;s<5;++s){ l[s]=__expf(l[s]-mx); sum+=l[s]; }
  float inv = 1.f/sum;
  #pragma unroll
  for (int s=0;s<5;++s) wh[(size_t)s*Mloc + m] = l[s]*inv;
}

// ---------------- K2: PURE fc1 GEMM via bf16 MFMA: y1 = x @ fc1_w (bf16) ------
// Linearity: H-shift mix commutes with the GEMM. A = bf16(x) tile [64][96],
// LDS pitch 100 ushorts (200B) -> all 16 fragment rows on distinct banks.
__global__ __launch_bounds__(256) void k_fc1(const float* __restrict__ x,
    const unsigned short* __restrict__ Bp1, unsigned short* __restrict__ y1,
    int base, int Mloc){
  __shared__ unsigned short As[64][100];   // 12800 B
  const int tid = threadIdx.x;
  const int m0 = blockIdx.x*64;
  {
    const int sr = tid>>2, sq = tid&3;
    const float* src = &x[(size_t)(base + m0 + sr)*Cc + sq*24];
    #pragma unroll
    for (int p=0;p<3;++p){
      float4 v0 = *(const float4*)&src[p*8];
      float4 v1 = *(const float4*)&src[p*8+4];
      us8 ov;
      ov[0]=f2b(v0.x); ov[1]=f2b(v0.y); ov[2]=f2b(v0.z); ov[3]=f2b(v0.w);
      ov[4]=f2b(v1.x); ov[5]=f2b(v1.y); ov[6]=f2b(v1.z); ov[7]=f2b(v1.w);
      *(us8*)&As[sr][sq*24 + p*8] = ov;
    }
  }
  __syncthreads();

  const int wv = tid>>6, l = tid&63;
  const int row16 = l&15, g = l>>4;
  f4v acc[24];
  #pragma unroll
  for (int nt=0;nt<24;++nt) acc[nt] = (f4v){0.f,0.f,0.f,0.f};

  #pragma unroll
  for (int ks=0;ks<3;++ks){
    s8v a = *(const s8v*)&As[wv*16 + row16][ks*32 + g*8];
    #pragma unroll
    for (int nt=0;nt<24;++nt){
      s8v b = *(const s8v*)&Bp1[((size_t)(nt*3+ks)*64 + l)*8];
      acc[nt] = __builtin_amdgcn_mfma_f32_16x16x32_bf16(a, b, acc[nt], 0, 0, 0);
    }
  }

  #pragma unroll
  for (int nt=0;nt<24;++nt){
    #pragma unroll
    for (int r=0;r<4;++r){
      size_t m = (size_t)(m0 + wv*16 + g*4 + r);
      y1[m*CH + nt*16 + row16] = f2b(acc[nt][r]);
    }
  }
}

// ---------------- K2b: H-shift blend: hid[m] = sum_i wh[i][m]*y1[m-(i-2)*128] + b1
__global__ __launch_bounds__(256) void k_blend_h(const unsigned short* __restrict__ y1,
    const float* __restrict__ wh, const float* __restrict__ fc1b,
    unsigned short* __restrict__ hid, int Mloc){
  const int tid = threadIdx.x;
  const int m0 = blockIdx.x*16;
  const int tl = tid>>4, q = tid&15;   // token, 24-ch slice
  const int ml = m0 + tl;
  const int sh = (ml>>7)&127;          // h coordinate (base is mult of 128 rows)
  float swgt[5];
  #pragma unroll
  for (int i=0;i<5;++i){
    int h2 = sh - (i-2);
    swgt[i] = ((unsigned)h2 < 128u) ? wh[(size_t)i*Mloc + ml] : 0.f;
  }
  const int c0 = q*24;
  float acc[24];
  #pragma unroll
  for (int j=0;j<24;++j) acc[j] = fc1b[c0+j];
  #pragma unroll
  for (int i=0;i<5;++i){
    if (swgt[i] != 0.f){
      const unsigned short* yr = &y1[(size_t)(ml-(i-2)*128)*CH + c0];
      #pragma unroll
      for (int p=0;p<3;++p){
        us8 v = *(const us8*)&yr[p*8];
        #pragma unroll
        for (int j=0;j<8;++j) acc[p*8+j] = fmaf(swgt[i], b2f(v[j]), acc[p*8+j]);
      }
    }
  }
  unsigned short* o = &hid[(size_t)ml*CH + c0];
  #pragma unroll
  for (int p=0;p<3;++p){
    us8 ov;
    #pragma unroll
    for (int j=0;j<8;++j) ov[j] = f2b(acc[p*8+j]);
    *(us8*)&o[p*8] = ov;
  }
}

// ---------------- K3: dwconv3x3 + bias + exact GELU + gate-W -> hid2, ww ----------------
__global__ __launch_bounds__(64) void k_dw(const unsigned short* __restrict__ hid,
    const float* __restrict__ wt_t, const float* __restrict__ dwb,
    const float* __restrict__ gww, const float* __restrict__ gwb,
    unsigned short* __restrict__ hid2, float* __restrict__ ww, int Mloc){
  const int tid = threadIdx.x;
  const int m0 = blockIdx.x*8;
  const int tl = tid>>3, cg = tid&7;
  const int m  = m0 + tl;                 // 8 consecutive tokens, same h row
  const int h = (m>>7)&127, w = m&127;
  bool ok[9];
  #pragma unroll
  for (int kh=0;kh<3;++kh)
    #pragma unroll
    for (int kw=0;kw<3;++kw)
      ok[kh*3+kw] = ((unsigned)(h+kh-1) < 128u) && ((unsigned)(w+kw-1) < 128u);

  float part[5] = {0.f,0.f,0.f,0.f,0.f};
  #pragma unroll 1
  for (int cc=0;cc<6;++cc){
    const int c = cg*8 + cc*64;
    float acc[8];
    {
      f8 bias = *(const f8*)&dwb[c];
      #pragma unroll
      for (int j=0;j<8;++j) acc[j] = bias[j];
    }
    #pragma unroll
    for (int kh=0;kh<3;++kh){
      us8 hv[3];
      #pragma unroll
      for (int kw=0;kw<3;++kw){
        if (ok[kh*3+kw]){
          hv[kw] = *(const us8*)&hid[(size_t)(m + (kh-1)*128 + (kw-1))*CH + c];
        } else {
          us8 z = {0,0,0,0,0,0,0,0};
          hv[kw] = z;
        }
      }
      #pragma unroll
      for (int kw=0;kw<3;++kw){
        f8 wf = *(const f8*)&wt_t[(kh*3+kw)*CH + c];
        #pragma unroll
        for (int j=0;j<8;++j)
          acc[j] = fmaf(b2f(hv[kw][j]), wf[j], acc[j]);
      }
    }
    float g[8];
    us8 ov;
    #pragma unroll
    for (int j=0;j<8;++j){
      float a = acc[j];
      g[j] = 0.5f*a*(1.f + erff(a*0.70710678118654752f));
      ov[j] = f2b(g[j]);
    }
    *(us8*)&hid2[(size_t)m*CH + c] = ov;
    #pragma unroll
    for (int s=0;s<5;++s){
      f8 gw = *(const f8*)&gww[s*CH + c];
      #pragma unroll
      for (int j=0;j<8;++j) part[s] = fmaf(g[j], gw[j], part[s]);
    }
  }
  #pragma unroll
  for (int s=0;s<5;++s){
    float v = part[s];
    v += __shfl_xor(v, 1, 64);
    v += __shfl_xor(v, 2, 64);
    v += __shfl_xor(v, 4, 64);
    part[s] = v;
  }
  if (cg==0){
    float l[5];
    #pragma unroll
    for (int s=0;s<5;++s) l[s] = part[s] + gwb[s];
    float mx = fmaxf(fmaxf(fmaxf(l[0],l[1]),fmaxf(l[2],l[3])),l[4]);
    float sum=0.f;
    #pragma unroll
    for (int s=0;s<5;++s){ l[s]=__expf(l[s]-mx); sum+=l[s]; }
    float inv=1.f/sum;
    #pragma unroll
    for (int s=0;s<5;++s) ww[(size_t)s*Mloc + m] = l[s]*inv;
  }
}

// ---------------- K4: PURE fc2 GEMM via bf16 MFMA: y = hid2 @ fc2w (bf16) -----
__global__ __launch_bounds__(256) void k_fc2(const unsigned short* __restrict__ hid2,
    const unsigned short* __restrict__ Bp, unsigned short* __restrict__ y,
    int Mloc){
  __shared__ unsigned short As[64][392];   // 50176 B
  const int tid = threadIdx.x;
  const int m0 = blockIdx.x*64;
  {
    const int sr = tid>>2, sq = tid&3;
    const unsigned short* src = &hid2[(size_t)(m0+sr)*CH + sq*96];
    #pragma unroll
    for (int cc=0;cc<12;++cc)
      *(us8*)&As[sr][sq*96 + cc*8] = *(const us8*)&src[cc*8];
  }
  __syncthreads();

  const int wv = tid>>6, l = tid&63;
  const int row16 = l&15, g = l>>4;
  f4v acc[6];
  #pragma unroll
  for (int nt=0;nt<6;++nt) acc[nt] = (f4v){0.f,0.f,0.f,0.f};

  #pragma unroll
  for (int ks=0;ks<12;++ks){
    s8v a = *(const s8v*)&As[wv*16 + row16][ks*32 + g*8];
    #pragma unroll
    for (int nt=0;nt<6;++nt){
      s8v b = *(const s8v*)&Bp[((size_t)(nt*12+ks)*64 + l)*8];
      acc[nt] = __builtin_amdgcn_mfma_f32_16x16x32_bf16(a, b, acc[nt], 0, 0, 0);
    }
  }

  #pragma unroll
  for (int nt=0;nt<6;++nt){
    #pragma unroll
    for (int r=0;r<4;++r){
      size_t m = (size_t)(m0 + wv*16 + g*4 + r);
      y[m*96 + nt*16 + row16] = f2b(acc[nt][r]);
    }
  }
}

// ---------------- K5: W-shift blend: out[m] = sum_i ww[i][m]*y[m-(i-2)] + b ---
__global__ __launch_bounds__(256) void k_blend(const unsigned short* __restrict__ y,
    const float* __restrict__ ww, const float* __restrict__ fc2b,
    float* __restrict__ out, int base, int Mloc){
  const int tid = threadIdx.x;
  const int m0 = blockIdx.x*64;
  const int tl = tid>>2, q = tid&3;   // token, 24-col quarter
  const int ml = m0 + tl;
  const int gm = base + ml;
  const int wp = gm & 127;
  float swgt[5];
  #pragma unroll
  for (int i=0;i<5;++i){
    int w2 = wp - (i-2);
    swgt[i] = ((unsigned)w2 < 128u) ? ww[(size_t)i*Mloc + ml] : 0.f;
  }
  const int c0 = q*24;
  float acc[24];
  #pragma unroll
  for (int j=0;j<24;++j) acc[j] = fc2b[c0+j];
  #pragma unroll
  for (int i=0;i<5;++i){
    if (swgt[i] != 0.f){
      const unsigned short* yr = &y[(size_t)(ml-(i-2))*96 + c0];
      #pragma unroll
      for (int p=0;p<3;++p){
        us8 v = *(const us8*)&yr[p*8];
        #pragma unroll
        for (int j=0;j<8;++j) acc[p*8+j] = fmaf(swgt[i], b2f(v[j]), acc[p*8+j]);
      }
    }
  }
  float* o = &out[(size_t)gm*96 + c0];
  #pragma unroll
  for (int p=0;p<6;++p)
    *(float4*)&o[p*4] = make_float4(acc[p*4],acc[p*4+1],acc[p*4+2],acc[p*4+3]);
}

extern "C" void kernel_launch(void* const* d_in, const int* in_sizes, int n_in,
                              void* d_out, int out_size, void* d_ws, size_t ws_size,
                              hipStream_t stream) {
  const float* x     = (const float*)d_in[0];
  const float* fc1_w = (const float*)d_in[3];
  const float* fc1_b = (const float*)d_in[4];
  const float* dw_w  = (const float*)d_in[5];
  const float* dw_b  = (const float*)d_in[6];
  const float* fc2_w = (const float*)d_in[7];
  const float* fc2_b = (const float*)d_in[8];
  const float* gh_w  = (const float*)d_in[9];
  const float* gh_b  = (const float*)d_in[10];
  const float* gw_w  = (const float*)d_in[11];
  const float* gw_b  = (const float*)d_in[12];
  float* out = (float*)d_out;

  // ws: wt_t 13824 B | Bp2 73728 B | Bp1 73728 B | chunk scratch
  float* wt_t = (float*)d_ws;
  unsigned short* Bp  = (unsigned short*)((char*)d_ws + 13824);
  unsigned short* Bp1 = (unsigned short*)((char*)d_ws + 13824 + 73728);
  char*  wsc  = (char*)d_ws + 13824 + 73728 + 73728;
  size_t ws_rem = (ws_size > 161280) ? ws_size - 161280 : 0;

  k_wprep<<<(9*CH + 63)/64, 64, 0, stream>>>(dw_w, wt_t);
  k_wprep2<<<144, 256, 0, stream>>>(fc2_w, Bp);
  k_wprep1<<<144, 256, 0, stream>>>(fc1_w, Bp1);

  // per-image: wh+ww 5*Mi*4*2 | hid+hid2 Mi*384*2*2 | y1 Mi*384*2 (y aliases y1)
  const size_t pi = (size_t)5*Mi*4*2 + (size_t)Mi*CH*2*2 + (size_t)Mi*CH*2;
  int NI = (int)(ws_rem / pi);
  if (NI < 1) NI = 1;
  if (NI > 16) NI = 16;

  for (int b0 = 0; b0 < 16; b0 += NI) {
    int nb = (16 - b0 < NI) ? (16 - b0) : NI;
    int Mloc = nb * Mi;
    int base = b0 * Mi;
    float* wh = (float*)wsc;
    float* ww = wh + (size_t)5*Mloc;
    unsigned short* hid  = (unsigned short*)(ww + (size_t)5*Mloc);
    unsigned short* hid2 = hid + (size_t)Mloc*CH;
    unsigned short* y1   = hid2 + (size_t)Mloc*CH;   // M*384 bf16
    unsigned short* yb   = y1;                        // y aliases y1 (y1 dead by k_fc2)
    k_gate_h<<<Mloc/256, 256, 0, stream>>>(x, gh_w, gh_b, wh, base, Mloc);
    k_fc1<<<Mloc/64, 256, 0, stream>>>(x, Bp1, y1, base, Mloc);
    k_blend_h<<<Mloc/16, 256, 0, stream>>>(y1, wh, fc1_b, hid, Mloc);
    k_dw<<<Mloc/8, 64, 0, stream>>>(hid, wt_t, dw_b, gw_w, gw_b, hid2, ww, Mloc);
    k_fc2<<<Mloc/64, 256, 0, stream>>>(hid2, Bp, yb, Mloc);
    k_blend<<<Mloc/64, 256, 0, stream>>>(yb, ww, fc2_b, out, base, Mloc);
  }
}